// Round 5
// baseline (200794.409 us; speedup 1.0000x reference)
//
#include <hip/hip_runtime.h>
#include <hip/hip_bf16.h>

// B=32, T_ENC=512, steps TD=501, D_ENC=512, N_MEL=160, H=1024, 4H=4096
// aLSTM K = 256(pre)+512(ctx)+1024(ah) = 1792 ; dLSTM K = 512(ctx)+1024(ah)+1024(dh) = 2560
// Persistent kernel v4: LDS-resident gate weights; CACHED cross-phase traffic with
// release/acquire fences at barriers (buffer_wbl2 / buffer_inv), relaxed spin;
// conv fused into attention; out_proj partitioned by output row; 5 barriers/step.
// v3 lesson: agent-scope atomics don't coalesce (1 fabric txn per lane) -> 11M txn/step.

typedef __hip_bfloat16 bf16;

__device__ __forceinline__ float b2f(bf16 x){ return __bfloat162float(x); }
__device__ __forceinline__ bf16 f2b(float x){ return __float2bfloat16(x); }
__device__ __forceinline__ unsigned short f2bu(float x){
  union { bf16 h; unsigned short u; } cv; cv.h = __float2bfloat16(x); return cv.u;
}
__device__ __forceinline__ float us2f(unsigned short u){
  return __uint_as_float(((unsigned)u) << 16);
}
__device__ __forceinline__ float sig_s(float x){
  if (x > 30.f) return 1.f; if (x < -30.f) return 0.f;
  return 1.f/(1.f+__expf(-x)); }
__device__ __forceinline__ float tanh_s(float x){
  if (x > 15.f) return 1.f; if (x < -15.f) return -1.f;
  float e=__expf(2.f*x); return 1.f-2.f/(e+1.f); }

// ---------------- workspace layout (fp32 elements unless noted) ----------------
constexpr size_t S_MKT   = 32ull*128*512;
constexpr size_t OFF_MKT = 0;
constexpr size_t OFF_AC  = OFF_MKT + S_MKT;
constexpr size_t OFF_DC  = OFF_AC + 32*1024;
constexpr size_t OFF_AW  = OFF_DC + 32*1024;
constexpr size_t OFF_AWT = OFF_AW + 32*512;
constexpr size_t OFF_BARS= OFF_AWT + 32*512;         // 3072 uints (zeroed)
constexpr size_t OFF_XA  = OFF_BARS + 3072;          // xcatA [32][1792] = [pre|ctx|ah]
constexpr size_t ZERO_LEN = OFF_XA - OFF_AC;
constexpr size_t OFF_XD  = OFF_XA + 32*1792;         // xcatD [32][2560] = [ctx|ah|dh]
constexpr size_t OFF_GPA = OFF_XD + 32*2560;         // 8 chunks x 32 x 4096
constexpr size_t OFF_GPD = OFF_GPA + 8ull*32*4096;   // 8 chunks x 32 x 4096
constexpr size_t OFF_RED = OFF_GPD + 8ull*32*4096;   // redG [32][8][2]
constexpr size_t OFF_BIASA = OFF_RED + 512;
constexpr size_t OFF_BIASD = OFF_BIASA + 4096;
constexpr size_t OFF_WFOLD = OFF_BIASD + 4096;       // 128 x 62
constexpr size_t OFF_QBIAS = OFF_WFOLD + 7936;       // 128 = bq + bl + wl@conv_b
constexpr size_t OFF_WQT   = OFF_QBIAS + 128;        // wqT [1024][128]
constexpr size_t OFF_F32_END = OFF_WQT + 1024*128;

constexpr size_t OFF_PRE2B_BYTES = ((OFF_F32_END*4 + 255)/256)*256;
constexpr size_t S_PRE2B = 501ull*32*256;                       // bf16
constexpr size_t OFF_WAT_BYTES = ((OFF_PRE2B_BYTES + S_PRE2B*2 + 255)/256)*256;
constexpr size_t S_WAT = 1792ull*4096;                          // bf16, per-block slices
constexpr size_t OFF_WDT_BYTES = OFF_WAT_BYTES + S_WAT*2;
constexpr size_t S_WDT = 2560ull*4096;
constexpr size_t WS_NEEDED = OFF_WDT_BYTES + S_WDT*2;           // ~62 MB

// LDS: Wa slice 57344 B | Wd slice 81920 B | scratch 23552 B
constexpr int LDS_WA = 57344;
constexpr int LDS_WD = 81920;
constexpr int LDS_SCR = 23552;
constexpr int SMEM_TOTAL = LDS_WA + LDS_WD + LDS_SCR;   // 162,816 <= 163,840

// output offsets (fp32 elements in d_out)
constexpr size_t OUT_MEL  = 0;
constexpr size_t OUT_GATE = 501ull*32*160;
constexpr size_t OUT_ATTN = OUT_GATE + 501ull*32;

// ---------------- prep kernels ----------------
__global__ void k_zero(float* __restrict__ p, int n){
  int i = blockIdx.x*256 + threadIdx.x;
  if (i < n) p[i] = 0.f;
}

__global__ void k_bias(const float* __restrict__ b1, const float* __restrict__ b2,
                       float* __restrict__ out){
  int i = blockIdx.x*256 + threadIdx.x;
  if (i < 4096) out[i] = b1[i] + b2[i];
}

// fold wl (128x32) into conv weights (32x62) -> wfold[128][62]; qbias = bq+bl+wl@cb
__global__ void k_fold(const float* __restrict__ cw, const float* __restrict__ cb,
                       const float* __restrict__ wl, const float* __restrict__ bl,
                       const float* __restrict__ bq,
                       float* __restrict__ wfold, float* __restrict__ qbias){
  int c = threadIdx.x;  // 128 threads, 1 block
  for (int kk = 0; kk < 62; ++kk){
    float a = 0.f;
    for (int o = 0; o < 32; ++o) a += wl[c*32 + o]*cw[o*62 + kk];
    wfold[c*62 + kk] = a;
  }
  float q = bq[c] + bl[c];
  for (int o = 0; o < 32; ++o) q += wl[c*32 + o]*cb[o];
  qbias[c] = q;
}

// wqT[k][c] = wq[c][k]
__global__ __launch_bounds__(256) void k_wqT(const float* __restrict__ wq,
                                             float* __restrict__ wqT){
  int idx = blockIdx.x*256 + threadIdx.x;
  int k = idx >> 7, c = idx & 127;
  wqT[idx] = wq[(size_t)c*1024 + k];
}

// W^T bf16, laid out as per-block contiguous LDS slices:
// slice = (kc*32 + jt); within: (klocal>>2)*512 + jl*4 + (klocal&3)  (ushorts)
__global__ __launch_bounds__(256) void k_trans(const float* __restrict__ src, int C,
    unsigned short* __restrict__ dst, int koff, int CH, int SLICE){
  __shared__ unsigned short tile[64][65];
  int r0 = blockIdx.x*64, c0 = blockIdx.y*64;
  int tx = threadIdx.x & 63, ty = threadIdx.x >> 6;
  for (int rr = ty; rr < 64; rr += 4)
    tile[rr][tx] = f2bu(src[(size_t)(r0+rr)*C + c0 + tx]);
  __syncthreads();
  for (int rr = ty; rr < 64; rr += 4){
    int k = koff + c0 + rr;
    int kcc = k / CH, kl = k - kcc*CH;
    int j = r0 + tx, jtt = j >> 7, jl = j & 127;
    dst[(size_t)(kcc*32 + jtt)*SLICE + (size_t)(kl >> 2)*512 + jl*4 + (kl & 3)] = tile[tx][rr];
  }
}

// prenet -> pre2b[tt][b][j] (bf16)
__global__ __launch_bounds__(256) void k_prenet(const float* __restrict__ mels,
    const float* __restrict__ w1, const float* __restrict__ b1,
    const float* __restrict__ w2, const float* __restrict__ b2,
    bf16* __restrict__ pre2){
  __shared__ float mel[160];
  __shared__ float x1[256];
  int b = blockIdx.x, tid = threadIdx.x;
  for (int ti = 0; ti < 8; ++ti){
    int tt = blockIdx.y*8 + ti;
    if (tt >= 501) break;
    if (tid < 160) mel[tid] = (tt == 0) ? 0.f : mels[((size_t)b*500 + (tt-1))*160 + tid];
    __syncthreads();
    float a = b1[tid];
    for (int k = 0; k < 160; ++k) a += mel[k]*w1[tid*160 + k];
    x1[tid] = fmaxf(a, 0.f);
    __syncthreads();
    float a2 = b2[tid];
    for (int k = 0; k < 256; ++k) a2 += x1[k]*w2[tid*256 + k];
    pre2[((size_t)tt*32 + b)*256 + tid] = f2b(fmaxf(a2, 0.f));
    __syncthreads();
  }
}

// mkT[b][c][t] = dot(enc[b][t][:], wk[c][:]) + bk[c]
__global__ __launch_bounds__(128) void k_memkeys(const float* __restrict__ enc,
    const float* __restrict__ wk, const float* __restrict__ bk, float* __restrict__ mkT){
  __shared__ float er[512];
  int b = blockIdx.x, tid = threadIdx.x;
  for (int i = 0; i < 8; ++i){
    int t = blockIdx.y*8 + i;
    const float* e = enc + ((size_t)b*512 + t)*512;
    for (int k = tid; k < 512; k += 128) er[k] = e[k];
    __syncthreads();
    float a = bk[tid];
    for (int k = 0; k < 512; ++k) a += er[k]*wk[tid*512 + k];
    mkT[((size_t)b*128 + tid)*512 + t] = a;
    __syncthreads();
  }
}

// ---------------- persistent decoder ----------------
// Barrier: per-instance counter (no reset/ABA). Arrival = RELEASE fetch_add
// (compiler emits vmem drain + buffer_wbl2 -> L2 writeback). Spin = RELAXED loads
// (no cache maintenance -> no invalidate storm). After all arrive: one ACQUIRE
// fence (buffer_inv) so subsequent cached loads see other XCDs' data.
__device__ __forceinline__ void gridbar(unsigned* cnt){
  asm volatile("s_waitcnt vmcnt(0) lgkmcnt(0)" ::: "memory");
  __syncthreads();
  if (threadIdx.x == 0){
    __hip_atomic_fetch_add(cnt, 1u, __ATOMIC_RELEASE, __HIP_MEMORY_SCOPE_AGENT);
    while (__hip_atomic_load(cnt, __ATOMIC_RELAXED, __HIP_MEMORY_SCOPE_AGENT) < 256u)
      __builtin_amdgcn_s_sleep(8);
  }
  __syncthreads();
  __builtin_amdgcn_fence(__ATOMIC_ACQUIRE, "agent");
}

// skinny-GEMM k-chunk partial from LDS-resident weights (cached x staging).
// block = (jt = blk&31, kc = blk>>5); threads 512 = 128 j x 4 b-groups(8 b).
template<int CH, int KS, int HK>
__device__ __forceinline__ void gates_phase(const unsigned short* __restrict__ smW,
    float* xs, const float* xcat, float* Gp, int jt, int kc, int tid){
  const int jl = tid & 127, bg = tid >> 7;
  constexpr int QPB = HK/4;        // float4 per b per half
  constexpr int NQ  = 32*QPB;      // total float4 per half
  float acc[8];
  #pragma unroll
  for (int i = 0; i < 8; ++i) acc[i] = 0.f;
  const int k0 = kc*CH;
  for (int h = 0; h < CH/HK; ++h){
    __syncthreads();
    for (int i = tid; i < NQ; i += 512){
      int b = i / QPB, kq = i - b*QPB;
      ((float4*)xs)[i] = *(const float4*)(xcat + (size_t)b*KS + k0 + h*HK + 4*kq);
    }
    __syncthreads();
    for (int kk = 0; kk < HK; kk += 4){
      const ushort4 w4 = *(const ushort4*)(smW + (size_t)((h*HK + kk) >> 2)*512 + jl*4);
      const float w0 = us2f(w4.x), w1 = us2f(w4.y), w2 = us2f(w4.z), w3 = us2f(w4.w);
      #pragma unroll
      for (int bb = 0; bb < 8; ++bb){
        const float4 xv = *(const float4*)&xs[(bg*8 + bb)*HK + kk];
        acc[bb] = fmaf(xv.x, w0, acc[bb]);
        acc[bb] = fmaf(xv.y, w1, acc[bb]);
        acc[bb] = fmaf(xv.z, w2, acc[bb]);
        acc[bb] = fmaf(xv.w, w3, acc[bb]);
      }
    }
  }
  float* gp = Gp + (size_t)kc*131072 + (size_t)(bg*8)*4096 + jt*128 + jl;
  #pragma unroll
  for (int bb = 0; bb < 8; ++bb) gp[(size_t)bb*4096] = acc[bb];
}

// LSTM cell reduce: 32 blocks, thread owns a u-pair; cached float2 I/O.
__device__ __forceinline__ void cell_phase(const float* Gp,
    const float* __restrict__ bias, float* cst,
    float* h0, int h0stride, int h0off,
    float* h1, int h1stride, int h1off,
    int blk, int tid){
  int idx = (blk*512 + tid)*2;
  int b = idx >> 10, u = idx & 1023;
  float gi0 = bias[u],      gi1 = bias[u+1];
  float gf0 = bias[1024+u], gf1 = bias[1024+u+1];
  float gg0 = bias[2048+u], gg1 = bias[2048+u+1];
  float go0 = bias[3072+u], go1 = bias[3072+u+1];
  #pragma unroll
  for (int ci = 0; ci < 8; ++ci){
    const float* p = Gp + (size_t)ci*131072 + (size_t)b*4096 + u;
    float2 a = *(const float2*)p, f = *(const float2*)(p+1024);
    float2 g = *(const float2*)(p+2048), o = *(const float2*)(p+3072);
    gi0 += a.x; gi1 += a.y; gf0 += f.x; gf1 += f.y;
    gg0 += g.x; gg1 += g.y; go0 += o.x; go1 += o.y;
  }
  float2 cp = *(const float2*)(cst + idx);
  float cn0 = sig_s(gf0)*cp.x + sig_s(gi0)*tanh_s(gg0);
  float cn1 = sig_s(gf1)*cp.y + sig_s(gi1)*tanh_s(gg1);
  float2 hh = make_float2(sig_s(go0)*tanh_s(cn0), sig_s(go1)*tanh_s(cn1));
  *(float2*)(cst + idx) = make_float2(cn0, cn1);
  *(float2*)(h0 + (size_t)b*h0stride + h0off + u) = hh;
  if (h1) *(float2*)(h1 + (size_t)b*h1stride + h1off + u) = hh;
}

// out_proj partitioned by output row: block ob owns jo = {ob, ob+32, ..., ob+128}
// (+ gate row 160 for ob==31); per (jo,b) dot one wave-task.
__device__ __forceinline__ void out_proj_rows(int ob, int lane, int wv, int t,
    const float* xcatD, const float* __restrict__ wm,
    const float* __restrict__ bm, const float* __restrict__ wg,
    const float* __restrict__ bg,
    float* melOut, float* gateOut){
  const int NT = (ob == 31) ? 192 : 160;
  for (int task = wv; task < NT; task += 8){
    int r = task >> 5, b = task & 31;
    int jo = (r < 5) ? ob + 32*r : 160;
    const float* wrow = (jo < 160) ? (wm + (size_t)jo*1536) : wg;
    const float* xd = xcatD + (size_t)b*2560;
    float a = 0.f;
    for (int k = lane; k < 1536; k += 64){
      float x = (k < 1024) ? xd[1536 + k] : xd[k - 1024];   // h = [dh | ctx]
      a = fmaf(x, wrow[k], a);
    }
    #pragma unroll
    for (int off = 32; off; off >>= 1) a += __shfl_down(a, off, 64);
    if (lane == 0){
      if (jo < 160) melOut[((size_t)t*32 + b)*160 + jo] = a + bm[jo];
      else gateOut[t*32 + b] = a + bg[0];
    }
  }
}

__global__ __launch_bounds__(512) void k_decoder(
    const unsigned short* __restrict__ WaT, const unsigned short* __restrict__ WdT,
    const float* __restrict__ biasA, const float* __restrict__ biasD,
    const bf16* __restrict__ pre2b, const float* __restrict__ mkT,
    const float* __restrict__ enc, const unsigned char* __restrict__ mask,
    const float* __restrict__ wqT, const float* __restrict__ qbias,
    const float* __restrict__ wfold, const float* __restrict__ wa,
    const float* __restrict__ ba, const float* __restrict__ wm,
    const float* __restrict__ bm, const float* __restrict__ wg,
    const float* __restrict__ bg,
    float* xcatA, float* xcatD, float* ac, float* dc,
    float* aw, float* awt, float* GpA, float* GpD,
    float* redG, unsigned* bars,
    float* melOut, float* gateOut, float* attnOut)
{
  extern __shared__ __align__(16) char sm[];
  unsigned short* smWa = (unsigned short*)sm;
  unsigned short* smWd = (unsigned short*)(sm + LDS_WA);
  char* scr = sm + LDS_WA + LDS_WD;
  float* xs   = (float*)scr;               // gates staging [0,20480)
  float* ahS  = (float*)scr;               // P3 [0,4096)
  float* qpP  = (float*)(scr + 4096);      // P3 [4096,6144)
  float* sqS  = (float*)(scr + 6144);      // [6144,6656)
  float* eT   = (float*)(scr + 6656);      // [6656,6912)  persists P3->P4
  float* sawL = (float*)(scr + 6912);      // [6912,7168)  persists P4 internal
  float* s0   = (float*)(scr + 7168);      // [7168,7552)
  float* s1   = (float*)(scr + 7552);      // [7552,7936)

  const int blk = blockIdx.x, tid = threadIdx.x;
  const int lane = tid & 63, wv = tid >> 6;
  const int jt = blk & 31, kc = blk >> 5;

  // ---- one-time: weight slices -> LDS; init xcat ----
  {
    const ushort4* sa = (const ushort4*)(WaT + (size_t)(kc*32 + jt)*28672);
    ushort4* da = (ushort4*)smWa;
    for (int i = tid; i < 7168; i += 512) da[i] = sa[i];
    const ushort4* sd = (const ushort4*)(WdT + (size_t)(kc*32 + jt)*40960);
    ushort4* dd = (ushort4*)smWd;
    for (int i = tid; i < 10240; i += 512) dd[i] = sd[i];
  }
  for (int idx = blk*512 + tid; idx < 32*1792; idx += 131072){
    int b = idx / 1792, i = idx - b*1792;
    xcatA[idx] = (i < 256) ? b2f(pre2b[b*256 + i]) : 0.f;
  }
  for (int idx = blk*512 + tid; idx < 32*2560; idx += 131072) xcatD[idx] = 0.f;

  int bi = 0;
  gridbar(bars + bi); ++bi;

  for (int t = 0; t < 501; ++t){
    // ---- P1: gatesA (all blocks) | cellD(t-1) (blocks 0..31) ----
    gates_phase<224, 1792, 112>(smWa, xs, xcatA, GpA, jt, kc, tid);
    if (blk < 32 && t > 0)
      cell_phase(GpD, biasD, dc, xcatD, 2560, 1536, nullptr, 0, 0, blk, tid);
    gridbar(bars + bi); ++bi;

    // ---- P2: cellA (0..31) | out(t-1) (64..95) | pre-stage(t+1) (96..127) ----
    if (blk < 32){
      cell_phase(GpA, biasA, ac, xcatA, 1792, 768, xcatD, 2560, 512, blk, tid);
    } else if (blk >= 64 && blk < 96){
      if (t > 0)
        out_proj_rows(blk-64, lane, wv, t-1, xcatD, wm, bm, wg, bg, melOut, gateOut);
    } else if (blk >= 96 && blk < 128){
      if (t < 500){
        int b = blk - 96;
        const bf16* ps = pre2b + ((size_t)(t+1)*32 + b)*256;
        for (int i = tid; i < 128; i += 512)
          *(float2*)(xcatA + (size_t)b*1792 + 2*i) =
              make_float2(b2f(ps[2*i]), b2f(ps[2*i+1]));
      }
    }
    gridbar(bars + bi); ++bi;

    // ---- P3: attention energies + fused conv (all blocks: b=blk>>3, tt=blk&7) ----
    {
      int b = blk >> 3, tt = blk & 7, t0 = tt*64;
      if (tid < 32){  // zero this block's ctx chunk (accumulated by P4 atomics)
        float2 z = make_float2(0.f, 0.f);
        *(float2*)(xcatA + (size_t)b*1792 + 256 + t0 + 2*tid) = z;
        *(float2*)(xcatD + (size_t)b*2560 + t0 + 2*tid) = z;
      }
      // stage conv windows: pos in [t0-15, t0+79), 94 each for aw and awt
      for (int i = tid; i < 188; i += 512){
        int ch = (i >= 94), p2 = ch ? i-94 : i;
        int pos = t0 + p2 - 15;
        float v = (pos >= 0 && pos < 512)
                ? (ch ? awt[b*512 + pos] : aw[b*512 + pos]) : 0.f;
        (ch ? s1 : s0)[p2] = v;
      }
      for (int i = tid; i < 512; i += 512)
        ((float2*)ahS)[i] = *(const float2*)(xcatA + (size_t)b*1792 + 768 + 2*i);
      __syncthreads();
      {  // query partials (redundant per b across its 8 tt-blocks; wqT L2-hot)
        int c = tid & 127, kq = tid >> 7;
        const float* ap = ahS + kq*256;
        const float* wp = wqT + (size_t)(kq*256)*128 + c;
        float p = 0.f;
        for (int k = 0; k < 256; ++k) p = fmaf(ap[k], wp[(size_t)k*128], p);
        qpP[kq*128 + c] = p;
      }
      __syncthreads();
      if (tid < 128)
        sqS[tid] = qpP[tid] + qpP[128+tid] + qpP[256+tid] + qpP[384+tid] + qbias[tid];
      __syncthreads();
      int tl = tid & 63, cg = tid >> 6;
      const float* mkb = mkT + (size_t)b*65536 + t0 + tl;
      float a = 0.f;
      for (int ci = 0; ci < 16; ++ci){
        int c = cg*16 + ci;
        const float* wf = wfold + c*62;   // lane-uniform -> scalar loads
        float lc = 0.f;
        #pragma unroll
        for (int k = 0; k < 31; ++k)
          lc = fmaf(wf[k], s0[tl+k], fmaf(wf[31+k], s1[tl+k], lc));
        float s = sqS[c] + mkb[(size_t)c*512] + lc;
        a = fmaf(tanh_s(s), wa[c], a);
      }
      qpP[cg*64 + tl] = a;
      __syncthreads();
      if (tid < 64){
        float e = ba[0];
        #pragma unroll
        for (int g = 0; g < 8; ++g) e += qpP[g*64 + tid];
        if (mask[b*512 + t0 + tid]) e = -1e30f;
        eT[tid] = e;
        float m = e;
        #pragma unroll
        for (int off = 32; off; off >>= 1) m = fmaxf(m, __shfl_xor(m, off, 64));
        float pe = __expf(e - m), ss = pe;
        #pragma unroll
        for (int off = 32; off; off >>= 1) ss += __shfl_xor(ss, off, 64);
        if (tid == 0)
          *(float2*)(redG + (size_t)(b*8 + tt)*2) = make_float2(m, ss);
      }
    }
    gridbar(bars + bi); ++bi;

    // ---- P4: softmax finish + ctx partial (atomic reduce) ----
    {
      int b = blk >> 3, tt = blk & 7, t0 = tt*64;
      if (tid < 64){
        float M = -1e30f, S = 0.f;
        float2 ms[8];
        #pragma unroll
        for (int i = 0; i < 8; ++i){
          ms[i] = *(const float2*)(redG + (size_t)(b*8 + i)*2);
          M = fmaxf(M, ms[i].x);
        }
        #pragma unroll
        for (int i = 0; i < 8; ++i) S += ms[i].y*__expf(ms[i].x - M);
        float av = __expf(eT[tid] - M)/S;
        int tg = t0 + tid;
        aw[b*512 + tg] = av;
        awt[b*512 + tg] += av;
        attnOut[((size_t)t*32 + b)*512 + tg] = av;
        sawL[tid] = av;
      }
      __syncthreads();
      {
        float accd = 0.f;
        const float* eb = enc + ((size_t)b*512 + t0)*512 + tid;
        for (int tau = 0; tau < 64; ++tau) accd = fmaf(sawL[tau], eb[(size_t)tau*512], accd);
        __hip_atomic_fetch_add(xcatA + (size_t)b*1792 + 256 + tid, accd,
                               __ATOMIC_RELAXED, __HIP_MEMORY_SCOPE_AGENT);
        __hip_atomic_fetch_add(xcatD + (size_t)b*2560 + tid, accd,
                               __ATOMIC_RELAXED, __HIP_MEMORY_SCOPE_AGENT);
      }
    }
    gridbar(bars + bi); ++bi;

    // ---- P5: gatesD (all blocks, LDS weights) ----
    gates_phase<320, 2560, 160>(smWd, xs, xcatD, GpD, jt, kc, tid);
    gridbar(bars + bi); ++bi;
  }

  // ---- epilogue: cellD(500), then out_proj(500) ----
  if (blk < 32)
    cell_phase(GpD, biasD, dc, xcatD, 2560, 1536, nullptr, 0, 0, blk, tid);
  gridbar(bars + bi); ++bi;
  if (blk >= 64 && blk < 96)
    out_proj_rows(blk-64, lane, wv, 500, xcatD, wm, bm, wg, bg, melOut, gateOut);
}

// ---------------- launch ----------------
extern "C" void kernel_launch(void* const* d_in, const int* in_sizes, int n_in,
                              void* d_out, int out_size, void* d_ws, size_t ws_size,
                              hipStream_t stream){
  if (ws_size < WS_NEEDED) return;  // diagnostic: absmax==max|ref| => ws too small

  const float* enc    = (const float*)d_in[0];
  const float* mels   = (const float*)d_in[1];
  const unsigned char* mask = (const unsigned char*)d_in[2];
  const float* w_pre1 = (const float*)d_in[3];
  const float* b_pre1 = (const float*)d_in[4];
  const float* w_pre2 = (const float*)d_in[5];
  const float* b_pre2 = (const float*)d_in[6];
  const float* wih_a  = (const float*)d_in[7];
  const float* whh_a  = (const float*)d_in[8];
  const float* bih_a  = (const float*)d_in[9];
  const float* bhh_a  = (const float*)d_in[10];
  const float* wq     = (const float*)d_in[11];
  const float* bq     = (const float*)d_in[12];
  const float* wk     = (const float*)d_in[13];
  const float* bk     = (const float*)d_in[14];
  const float* conv_w = (const float*)d_in[15];
  const float* conv_b = (const float*)d_in[16];
  const float* wl     = (const float*)d_in[17];
  const float* bl     = (const float*)d_in[18];
  const float* wa     = (const float*)d_in[19];
  const float* ba     = (const float*)d_in[20];
  const float* wih_d  = (const float*)d_in[21];
  const float* whh_d  = (const float*)d_in[22];
  const float* bih_d  = (const float*)d_in[23];
  const float* bhh_d  = (const float*)d_in[24];
  const float* wm     = (const float*)d_in[25];
  const float* bm     = (const float*)d_in[26];
  const float* wg     = (const float*)d_in[27];
  const float* bg     = (const float*)d_in[28];

  float* W = (float*)d_ws;
  float* mkT   = W + OFF_MKT;
  float* ac    = W + OFF_AC;
  float* dc    = W + OFF_DC;
  float* aw    = W + OFF_AW;
  float* awt   = W + OFF_AWT;
  unsigned* bars = (unsigned*)(W + OFF_BARS);
  float* xcatA = W + OFF_XA;
  float* xcatD = W + OFF_XD;
  float* GpA   = W + OFF_GPA;
  float* GpD   = W + OFF_GPD;
  float* redG  = W + OFF_RED;
  float* biasA = W + OFF_BIASA;
  float* biasD = W + OFF_BIASD;
  float* wfold = W + OFF_WFOLD;
  float* qbias = W + OFF_QBIAS;
  float* wqT   = W + OFF_WQT;
  unsigned short* WaT = (unsigned short*)((char*)d_ws + OFF_WAT_BYTES);
  unsigned short* WdT = (unsigned short*)((char*)d_ws + OFF_WDT_BYTES);
  bf16* pre2b = (bf16*)((char*)d_ws + OFF_PRE2B_BYTES);

  float* out    = (float*)d_out;
  float* melOut = out + OUT_MEL;
  float* gateOut= out + OUT_GATE;
  float* attnOut= out + OUT_ATTN;

  static int smem_set = 0;
  if (!smem_set){
    hipFuncSetAttribute((const void*)k_decoder,
                        hipFuncAttributeMaxDynamicSharedMemorySize, SMEM_TOTAL);
    smem_set = 1;
  }

  // ---- prep ----
  k_zero<<<(int)((ZERO_LEN + 255)/256), 256, 0, stream>>>(W + OFF_AC, (int)ZERO_LEN);
  k_bias<<<16, 256, 0, stream>>>(bih_a, bhh_a, biasA);
  k_bias<<<16, 256, 0, stream>>>(bih_d, bhh_d, biasD);
  k_fold<<<1, 128, 0, stream>>>(conv_w, conv_b, wl, bl, bq, wfold, qbias);
  k_wqT<<<512, 256, 0, stream>>>(wq, wqT);
  k_trans<<<dim3(64, 12), 256, 0, stream>>>(wih_a, 768,  WaT, 0,    224, 28672);
  k_trans<<<dim3(64, 16), 256, 0, stream>>>(whh_a, 1024, WaT, 768,  224, 28672);
  k_trans<<<dim3(64, 24), 256, 0, stream>>>(wih_d, 1536, WdT, 0,    320, 40960);
  k_trans<<<dim3(64, 16), 256, 0, stream>>>(whh_d, 1024, WdT, 1536, 320, 40960);
  k_prenet<<<dim3(32, 63), 256, 0, stream>>>(mels, w_pre1, b_pre1, w_pre2, b_pre2, pre2b);
  k_memkeys<<<dim3(32, 64), 128, 0, stream>>>(enc, wk, bk, mkT);

  // ---- the whole 501-step recurrence: one persistent kernel ----
  k_decoder<<<256, 512, SMEM_TOTAL, stream>>>(WaT, WdT, biasA, biasD, pre2b, mkT, enc, mask,
                                              wqT, qbias, wfold, wa, ba, wm, bm, wg, bg,
                                              xcatA, xcatD, ac, dc, aw, awt,
                                              GpA, GpD, redG, bars,
                                              melOut, gateOut, attnOut);
}

// Round 6
// 169863.831 us; speedup vs baseline: 1.1821x; 1.1821x over previous
//
#include <hip/hip_runtime.h>
#include <hip/hip_bf16.h>

// B=32, T_ENC=512, steps TD=501, D_ENC=512, N_MEL=160, H=1024, 4H=4096
// aLSTM K = 256(pre)+512(ctx)+1024(ah) = 1792 ; dLSTM K = 512(ctx)+1024(ah)+1024(dh) = 2560
// Persistent kernel v5: fence-free bypass coherence (v2b scheme, proven correct) +
//  (1) two-level tree barrier (16x16, per-counter cache lines) -- v2b's flat counter
//      serialized 256 RMWs on one line (~25-50us/barrier);
//  (2) gates accumulate via relaxed f32 atomics into GA/GD[32][4096] (no Gp partials);
//  (3) per-b LDS-staged out_proj, conv fused into attention, immutable data cached.

typedef __hip_bfloat16 bf16;

__device__ __forceinline__ float b2f(bf16 x){ return __bfloat162float(x); }
__device__ __forceinline__ bf16 f2b(float x){ return __float2bfloat16(x); }
__device__ __forceinline__ unsigned short f2bu(float x){
  union { bf16 h; unsigned short u; } cv; cv.h = __float2bfloat16(x); return cv.u;
}
__device__ __forceinline__ float us2f(unsigned short u){
  return __uint_as_float(((unsigned)u) << 16);
}
__device__ __forceinline__ float sig_s(float x){
  if (x > 30.f) return 1.f; if (x < -30.f) return 0.f;
  return 1.f/(1.f+__expf(-x)); }
__device__ __forceinline__ float tanh_s(float x){
  if (x > 15.f) return 1.f; if (x < -15.f) return -1.f;
  float e=__expf(2.f*x); return 1.f-2.f/(e+1.f); }

// coherent bypass load/store (agent scope, relaxed -> L2-bypass, no cache maintenance)
__device__ __forceinline__ float ld_cv(const float* p){
  return __hip_atomic_load(p, __ATOMIC_RELAXED, __HIP_MEMORY_SCOPE_AGENT);
}
__device__ __forceinline__ void st_cv(float* p, float v){
  __hip_atomic_store(p, v, __ATOMIC_RELAXED, __HIP_MEMORY_SCOPE_AGENT);
}
__device__ __forceinline__ float2 ld_cv2(const float* p){
  union { double d; float2 f; } u;
  u.d = __hip_atomic_load((const double*)p, __ATOMIC_RELAXED, __HIP_MEMORY_SCOPE_AGENT);
  return u.f;
}
__device__ __forceinline__ void st_cv2(float* p, float2 v){
  union { double d; float2 f; } u; u.f = v;
  __hip_atomic_store((double*)p, u.d, __ATOMIC_RELAXED, __HIP_MEMORY_SCOPE_AGENT);
}
__device__ __forceinline__ void at_add(float* p, float v){
  __hip_atomic_fetch_add(p, v, __ATOMIC_RELAXED, __HIP_MEMORY_SCOPE_AGENT);
}

// ---------------- workspace layout (fp32 elements unless noted) ----------------
constexpr size_t S_MKT   = 32ull*128*512;
constexpr size_t OFF_MKT = 0;
constexpr size_t OFF_AC  = OFF_MKT + S_MKT;
constexpr size_t OFF_DC  = OFF_AC + 32*1024;
constexpr size_t OFF_AW  = OFF_DC + 32*1024;
constexpr size_t OFF_AWT = OFF_AW + 32*512;
constexpr size_t OFF_BARS= OFF_AWT + 32*512;         // 2560 instances x 288 uints
constexpr size_t S_BARS  = 2560ull*288;
constexpr size_t OFF_GA  = OFF_BARS + S_BARS;        // 32 x 4096 accum
constexpr size_t OFF_GD  = OFF_GA + 32*4096;
constexpr size_t OFF_XA  = OFF_GD + 32*4096;         // xcatA [32][1792] = [pre|ctx|ah]
constexpr size_t ZERO_LEN = OFF_XA - OFF_AC;
constexpr size_t OFF_XD  = OFF_XA + 32*1792;         // xcatD [32][2560] = [ctx|ah|dh]
constexpr size_t OFF_RED = OFF_XD + 32*2560;         // redG [32][8][2]
constexpr size_t OFF_BIASA = OFF_RED + 512;
constexpr size_t OFF_BIASD = OFF_BIASA + 4096;
constexpr size_t OFF_WFOLD = OFF_BIASD + 4096;       // 128 x 62
constexpr size_t OFF_QBIAS = OFF_WFOLD + 7936;       // 128 = bq + bl + wl@conv_b
constexpr size_t OFF_WQT   = OFF_QBIAS + 128;        // wqT [1024][128]
constexpr size_t OFF_F32_END = OFF_WQT + 1024*128;

constexpr size_t OFF_PRE2B_BYTES = ((OFF_F32_END*4 + 255)/256)*256;
constexpr size_t S_PRE2B = 501ull*32*256;                       // bf16
constexpr size_t OFF_WAT_BYTES = ((OFF_PRE2B_BYTES + S_PRE2B*2 + 255)/256)*256;
constexpr size_t S_WAT = 1792ull*4096;                          // bf16, per-block slices
constexpr size_t OFF_WDT_BYTES = OFF_WAT_BYTES + S_WAT*2;
constexpr size_t S_WDT = 2560ull*4096;
constexpr size_t WS_NEEDED = OFF_WDT_BYTES + S_WDT*2;           // ~57.8 MB

// LDS: Wa slice 57344 B | Wd slice 81920 B | scratch 23552 B
constexpr int LDS_WA = 57344;
constexpr int LDS_WD = 81920;
constexpr int LDS_SCR = 23552;
constexpr int SMEM_TOTAL = LDS_WA + LDS_WD + LDS_SCR;   // 162,816 <= 163,840

// output offsets (fp32 elements in d_out)
constexpr size_t OUT_MEL  = 0;
constexpr size_t OUT_GATE = 501ull*32*160;
constexpr size_t OUT_ATTN = OUT_GATE + 501ull*32;

// ---------------- prep kernels ----------------
__global__ void k_zero(float* __restrict__ p, int n){
  int i = blockIdx.x*256 + threadIdx.x;
  if (i < n) p[i] = 0.f;
}

__global__ void k_bias(const float* __restrict__ b1, const float* __restrict__ b2,
                       float* __restrict__ out){
  int i = blockIdx.x*256 + threadIdx.x;
  if (i < 4096) out[i] = b1[i] + b2[i];
}

// fold wl (128x32) into conv weights (32x62) -> wfold[128][62]; qbias = bq+bl+wl@cb
__global__ void k_fold(const float* __restrict__ cw, const float* __restrict__ cb,
                       const float* __restrict__ wl, const float* __restrict__ bl,
                       const float* __restrict__ bq,
                       float* __restrict__ wfold, float* __restrict__ qbias){
  int c = threadIdx.x;  // 128 threads, 1 block
  for (int kk = 0; kk < 62; ++kk){
    float a = 0.f;
    for (int o = 0; o < 32; ++o) a += wl[c*32 + o]*cw[o*62 + kk];
    wfold[c*62 + kk] = a;
  }
  float q = bq[c] + bl[c];
  for (int o = 0; o < 32; ++o) q += wl[c*32 + o]*cb[o];
  qbias[c] = q;
}

// wqT[k][c] = wq[c][k]
__global__ __launch_bounds__(256) void k_wqT(const float* __restrict__ wq,
                                             float* __restrict__ wqT){
  int idx = blockIdx.x*256 + threadIdx.x;
  int k = idx >> 7, c = idx & 127;
  wqT[idx] = wq[(size_t)c*1024 + k];
}

// W^T bf16, laid out as per-block contiguous slices:
// slice = (kc*32 + jt); within: (klocal>>2)*512 + jl*4 + (klocal&3)  (ushorts)
__global__ __launch_bounds__(256) void k_trans(const float* __restrict__ src, int C,
    unsigned short* __restrict__ dst, int koff, int CH, int SLICE){
  __shared__ unsigned short tile[64][65];
  int r0 = blockIdx.x*64, c0 = blockIdx.y*64;
  int tx = threadIdx.x & 63, ty = threadIdx.x >> 6;
  for (int rr = ty; rr < 64; rr += 4)
    tile[rr][tx] = f2bu(src[(size_t)(r0+rr)*C + c0 + tx]);
  __syncthreads();
  for (int rr = ty; rr < 64; rr += 4){
    int k = koff + c0 + rr;
    int kcc = k / CH, kl = k - kcc*CH;
    int j = r0 + tx, jtt = j >> 7, jl = j & 127;
    dst[(size_t)(kcc*32 + jtt)*SLICE + (size_t)(kl >> 2)*512 + jl*4 + (kl & 3)] = tile[tx][rr];
  }
}

// prenet -> pre2b[tt][b][j] (bf16)
__global__ __launch_bounds__(256) void k_prenet(const float* __restrict__ mels,
    const float* __restrict__ w1, const float* __restrict__ b1,
    const float* __restrict__ w2, const float* __restrict__ b2,
    bf16* __restrict__ pre2){
  __shared__ float mel[160];
  __shared__ float x1[256];
  int b = blockIdx.x, tid = threadIdx.x;
  for (int ti = 0; ti < 8; ++ti){
    int tt = blockIdx.y*8 + ti;
    if (tt >= 501) break;
    if (tid < 160) mel[tid] = (tt == 0) ? 0.f : mels[((size_t)b*500 + (tt-1))*160 + tid];
    __syncthreads();
    float a = b1[tid];
    for (int k = 0; k < 160; ++k) a += mel[k]*w1[tid*160 + k];
    x1[tid] = fmaxf(a, 0.f);
    __syncthreads();
    float a2 = b2[tid];
    for (int k = 0; k < 256; ++k) a2 += x1[k]*w2[tid*256 + k];
    pre2[((size_t)tt*32 + b)*256 + tid] = f2b(fmaxf(a2, 0.f));
    __syncthreads();
  }
}

// mkT[b][c][t] = dot(enc[b][t][:], wk[c][:]) + bk[c]
__global__ __launch_bounds__(128) void k_memkeys(const float* __restrict__ enc,
    const float* __restrict__ wk, const float* __restrict__ bk, float* __restrict__ mkT){
  __shared__ float er[512];
  int b = blockIdx.x, tid = threadIdx.x;
  for (int i = 0; i < 8; ++i){
    int t = blockIdx.y*8 + i;
    const float* e = enc + ((size_t)b*512 + t)*512;
    for (int k = tid; k < 512; k += 128) er[k] = e[k];
    __syncthreads();
    float a = bk[tid];
    for (int k = 0; k < 512; ++k) a += er[k]*wk[tid*512 + k];
    mkT[((size_t)b*128 + tid)*512 + t] = a;
    __syncthreads();
  }
}

// ---------------- persistent decoder ----------------
// Two-level tree barrier, one instance per use (no reset/ABA). Layout per instance
// (288 uints): grp[g] at g*16 (16 groups, own line each), root at 256, go at 272.
// Arrival: vmcnt drain -> group RMW -> last-of-16 does root RMW -> last sets go.
// Everyone polls go with relaxed bypass loads (no invalidates).
__device__ __forceinline__ void gridbar(unsigned* base){
  asm volatile("s_waitcnt vmcnt(0) lgkmcnt(0)" ::: "memory");
  __syncthreads();
  if (threadIdx.x == 0){
    unsigned* grp  = base + ((blockIdx.x >> 4) << 4);
    unsigned* root = base + 256;
    unsigned* go   = base + 272;
    if (__hip_atomic_fetch_add(grp, 1u, __ATOMIC_RELAXED, __HIP_MEMORY_SCOPE_AGENT) == 15u){
      if (__hip_atomic_fetch_add(root, 1u, __ATOMIC_RELAXED, __HIP_MEMORY_SCOPE_AGENT) == 15u)
        __hip_atomic_store(go, 1u, __ATOMIC_RELAXED, __HIP_MEMORY_SCOPE_AGENT);
    }
    while (!__hip_atomic_load(go, __ATOMIC_RELAXED, __HIP_MEMORY_SCOPE_AGENT))
      __builtin_amdgcn_s_sleep(4);
  }
  __syncthreads();
}

// skinny-GEMM k-chunk from LDS-resident weights; accumulate into G via f32 atomics.
// block = (jt = blk&31, kc = blk>>5); threads 512 = 128 j x 4 b-groups(8 b).
template<int CH, int KS, int HK>
__device__ __forceinline__ void gates_phase(const unsigned short* __restrict__ smW,
    float* xs, const float* xcat, float* G, int jt, int kc, int tid){
  const int jl = tid & 127, bg = tid >> 7;
  float acc[8];
  #pragma unroll
  for (int i = 0; i < 8; ++i) acc[i] = 0.f;
  const int k0 = kc*CH;
  for (int h = 0; h < CH/HK; ++h){
    __syncthreads();
    for (int i = tid; i < 16*HK; i += 512){
      int b = i/(HK/2), kp = i - b*(HK/2);
      ((float2*)xs)[i] = ld_cv2(xcat + (size_t)b*KS + k0 + h*HK + 2*kp);
    }
    __syncthreads();
    for (int kk = 0; kk < HK; kk += 4){
      const ushort4 w4 = *(const ushort4*)(smW + (size_t)((h*HK + kk) >> 2)*512 + jl*4);
      const float w0 = us2f(w4.x), w1 = us2f(w4.y), w2 = us2f(w4.z), w3 = us2f(w4.w);
      #pragma unroll
      for (int bb = 0; bb < 8; ++bb){
        const float4 xv = *(const float4*)&xs[(bg*8 + bb)*HK + kk];
        acc[bb] = fmaf(xv.x, w0, acc[bb]);
        acc[bb] = fmaf(xv.y, w1, acc[bb]);
        acc[bb] = fmaf(xv.z, w2, acc[bb]);
        acc[bb] = fmaf(xv.w, w3, acc[bb]);
      }
    }
  }
  #pragma unroll
  for (int bb = 0; bb < 8; ++bb)
    at_add(G + (size_t)(bg*8 + bb)*4096 + jt*128 + jl, acc[bb]);
}

// LSTM cell: read accumulated G, re-zero it, apply nonlinearity, write h.
// 32 blocks x 512 threads, thread owns a u-pair.
__device__ __forceinline__ void cell_phase(float* G,
    const float* __restrict__ bias, float* cst,
    float* h0, int h0stride, int h0off,
    float* h1, int h1stride, int h1off,
    int blk, int tid){
  int idx = (blk*512 + tid)*2;
  int b = idx >> 10, u = idx & 1023;
  float* gb = G + (size_t)b*4096 + u;
  float2 gi = ld_cv2(gb), gf = ld_cv2(gb+1024), gg = ld_cv2(gb+2048), go = ld_cv2(gb+3072);
  float2 z = make_float2(0.f, 0.f);
  st_cv2(gb, z); st_cv2(gb+1024, z); st_cv2(gb+2048, z); st_cv2(gb+3072, z);
  gi.x += bias[u];      gi.y += bias[u+1];
  gf.x += bias[1024+u]; gf.y += bias[1024+u+1];
  gg.x += bias[2048+u]; gg.y += bias[2048+u+1];
  go.x += bias[3072+u]; go.y += bias[3072+u+1];
  float2 cp = *(const float2*)(cst + idx);       // cell state is block-private: cached
  float cn0 = sig_s(gf.x)*cp.x + sig_s(gi.x)*tanh_s(gg.x);
  float cn1 = sig_s(gf.y)*cp.y + sig_s(gi.y)*tanh_s(gg.y);
  float2 hh = make_float2(sig_s(go.x)*tanh_s(cn0), sig_s(go.y)*tanh_s(cn1));
  *(float2*)(cst + idx) = make_float2(cn0, cn1);
  st_cv2(h0 + (size_t)b*h0stride + h0off + u, hh);
  if (h1) st_cv2(h1 + (size_t)b*h1stride + h1off + u, hh);
}

// output projection for one b: stage xcatD row into LDS once, 161 dots over 8 waves.
__device__ __forceinline__ void out_proj_b(int b, int tid, int lane, int wv, int t,
    const float* xcatD, const float* __restrict__ wm,
    const float* __restrict__ bm, const float* __restrict__ wg,
    const float* __restrict__ bg,
    float* melOut, float* gateOut, float* xdS){
  for (int i = tid; i < 1280; i += 512)
    ((float2*)xdS)[i] = ld_cv2(xcatD + (size_t)b*2560 + 2*i);
  __syncthreads();
  for (int jo = wv; jo < 161; jo += 8){
    const float* wrow = (jo < 160) ? (wm + (size_t)jo*1536) : wg;
    float a = 0.f;
    for (int k = lane; k < 1536; k += 64){
      float x = (k < 1024) ? xdS[1536 + k] : xdS[k - 1024];   // h = [dh | ctx]
      a = fmaf(x, wrow[k], a);
    }
    #pragma unroll
    for (int off = 32; off; off >>= 1) a += __shfl_down(a, off, 64);
    if (lane == 0){
      if (jo < 160) melOut[((size_t)t*32 + b)*160 + jo] = a + bm[jo];
      else gateOut[t*32 + b] = a + bg[0];
    }
  }
}

__global__ __launch_bounds__(512) void k_decoder(
    const unsigned short* __restrict__ WaT, const unsigned short* __restrict__ WdT,
    const float* __restrict__ biasA, const float* __restrict__ biasD,
    const bf16* __restrict__ pre2b, const float* __restrict__ mkT,
    const float* __restrict__ enc, const unsigned char* __restrict__ mask,
    const float* __restrict__ wqT, const float* __restrict__ qbias,
    const float* __restrict__ wfold, const float* __restrict__ wa,
    const float* __restrict__ ba, const float* __restrict__ wm,
    const float* __restrict__ bm, const float* __restrict__ wg,
    const float* __restrict__ bg,
    float* xcatA, float* xcatD, float* ac, float* dc,
    float* aw, float* awt, float* GA, float* GD,
    float* redG, unsigned* bars,
    float* melOut, float* gateOut, float* attnOut)
{
  extern __shared__ __align__(16) char sm[];
  unsigned short* smWa = (unsigned short*)sm;
  unsigned short* smWd = (unsigned short*)(sm + LDS_WA);
  char* scr = sm + LDS_WA + LDS_WD;
  float* xs   = (float*)scr;               // gates staging [0,20480)
  float* xdS  = (float*)scr;               // out_proj [0,10240)
  float* ahS  = (float*)scr;               // P3 [0,4096)
  float* qpP  = (float*)(scr + 4096);      // P3 [4096,6144)
  float* sqS  = (float*)(scr + 6144);      // [6144,6656)
  float* eT   = (float*)(scr + 6656);      // [6656,6912)  persists P3->P4
  float* sawL = (float*)(scr + 6912);      // [6912,7168)  P4 internal
  float* s0   = (float*)(scr + 7168);      // [7168,7552)
  float* s1   = (float*)(scr + 7552);      // [7552,7936)

  const int blk = blockIdx.x, tid = threadIdx.x;
  const int lane = tid & 63, wv = tid >> 6;
  const int jt = blk & 31, kc = blk >> 5;

  // ---- one-time: weight slices -> LDS; init xcat (bypass stores!) ----
  {
    const ushort4* sa = (const ushort4*)(WaT + (size_t)(kc*32 + jt)*28672);
    ushort4* da = (ushort4*)smWa;
    for (int i = tid; i < 7168; i += 512) da[i] = sa[i];
    const ushort4* sd = (const ushort4*)(WdT + (size_t)(kc*32 + jt)*40960);
    ushort4* dd = (ushort4*)smWd;
    for (int i = tid; i < 10240; i += 512) dd[i] = sd[i];
  }
  for (int idx = blk*512 + tid; idx < 32*1792; idx += 131072){
    int b = idx / 1792, i = idx - b*1792;
    st_cv(xcatA + idx, (i < 256) ? b2f(pre2b[b*256 + i]) : 0.f);
  }
  for (int idx = blk*512 + tid; idx < 32*2560; idx += 131072) st_cv(xcatD + idx, 0.f);

  int bi = 0;
  gridbar(bars + (size_t)(bi++)*288);

  for (int t = 0; t < 501; ++t){
    // ---- P1: gatesA (all blocks, atomics into GA) | cellD(t-1) (blocks 0..31) ----
    gates_phase<224, 1792, 112>(smWa, xs, xcatA, GA, jt, kc, tid);
    if (blk < 32 && t > 0)
      cell_phase(GD, biasD, dc, xcatD, 2560, 1536, nullptr, 0, 0, blk, tid);
    gridbar(bars + (size_t)(bi++)*288);

    // ---- P2: cellA (0..31) | out(t-1) (64..95) | pre-stage(t+1) (96..127) ----
    if (blk < 32){
      cell_phase(GA, biasA, ac, xcatA, 1792, 768, xcatD, 2560, 512, blk, tid);
    } else if (blk >= 64 && blk < 96){
      if (t > 0)
        out_proj_b(blk-64, tid, lane, wv, t-1, xcatD, wm, bm, wg, bg,
                   melOut, gateOut, xdS);
    } else if (blk >= 96 && blk < 128){
      if (t < 500){
        int b = blk - 96;
        const bf16* ps = pre2b + ((size_t)(t+1)*32 + b)*256;
        for (int i = tid; i < 128; i += 512)
          st_cv2(xcatA + (size_t)b*1792 + 2*i,
                 make_float2(b2f(ps[2*i]), b2f(ps[2*i+1])));
      }
    }
    gridbar(bars + (size_t)(bi++)*288);

    // ---- P3: attention energies + fused conv (all blocks: b=blk>>3, tt=blk&7) ----
    {
      int b = blk >> 3, tt = blk & 7, t0 = tt*64;
      if (tid < 32){  // zero this block's ctx chunk (accumulated by P4 atomics)
        float2 z = make_float2(0.f, 0.f);
        st_cv2(xcatA + (size_t)b*1792 + 256 + t0 + 2*tid, z);
        st_cv2(xcatD + (size_t)b*2560 + t0 + 2*tid, z);
      }
      // stage conv windows: pos in [t0-15, t0+79), 94 each for aw and awt
      for (int i = tid; i < 188; i += 512){
        int ch = (i >= 94), p2 = ch ? i-94 : i;
        int pos = t0 + p2 - 15;
        float v = (pos >= 0 && pos < 512)
                ? (ch ? ld_cv(awt + b*512 + pos) : ld_cv(aw + b*512 + pos)) : 0.f;
        (ch ? s1 : s0)[p2] = v;
      }
      if (tid < 512)
        ((float2*)ahS)[tid] = ld_cv2(xcatA + (size_t)b*1792 + 768 + 2*tid);
      __syncthreads();
      {  // query partials (redundant per b across its 8 tt-blocks; wqT L2-hot)
        int c = tid & 127, kq = tid >> 7;
        const float* ap = ahS + kq*256;
        const float* wp = wqT + (size_t)(kq*256)*128 + c;
        float p = 0.f;
        for (int k = 0; k < 256; ++k) p = fmaf(ap[k], wp[(size_t)k*128], p);
        qpP[kq*128 + c] = p;
      }
      __syncthreads();
      if (tid < 128)
        sqS[tid] = qpP[tid] + qpP[128+tid] + qpP[256+tid] + qpP[384+tid] + qbias[tid];
      __syncthreads();
      int tl = tid & 63, cg = tid >> 6;
      const float* mkb = mkT + (size_t)b*65536 + t0 + tl;
      float a = 0.f;
      for (int ci = 0; ci < 16; ++ci){
        int c = cg*16 + ci;
        const float* wf = wfold + c*62;   // lane-uniform -> scalar loads
        float lc = 0.f;
        #pragma unroll
        for (int k = 0; k < 31; ++k)
          lc = fmaf(wf[k], s0[tl+k], fmaf(wf[31+k], s1[tl+k], lc));
        float s = sqS[c] + mkb[(size_t)c*512] + lc;
        a = fmaf(tanh_s(s), wa[c], a);
      }
      qpP[cg*64 + tl] = a;
      __syncthreads();
      if (tid < 64){
        float e = ba[0];
        #pragma unroll
        for (int g = 0; g < 8; ++g) e += qpP[g*64 + tid];
        if (mask[b*512 + t0 + tid]) e = -1e30f;
        eT[tid] = e;
        float m = e;
        #pragma unroll
        for (int off = 32; off; off >>= 1) m = fmaxf(m, __shfl_xor(m, off, 64));
        float pe = __expf(e - m), ss = pe;
        #pragma unroll
        for (int off = 32; off; off >>= 1) ss += __shfl_xor(ss, off, 64);
        if (tid == 0)
          st_cv2(redG + (size_t)(b*8 + tt)*2, make_float2(m, ss));
      }
    }
    gridbar(bars + (size_t)(bi++)*288);

    // ---- P4: softmax finish + ctx partial (atomic reduce) ----
    {
      int b = blk >> 3, tt = blk & 7, t0 = tt*64;
      if (tid < 64){
        float M = -1e30f, S = 0.f;
        float2 ms[8];
        #pragma unroll
        for (int i = 0; i < 8; ++i){
          ms[i] = ld_cv2(redG + (size_t)(b*8 + i)*2);
          M = fmaxf(M, ms[i].x);
        }
        #pragma unroll
        for (int i = 0; i < 8; ++i) S += ms[i].y*__expf(ms[i].x - M);
        float av = __expf(eT[tid] - M)/S;
        int tg = t0 + tid;
        st_cv(aw + b*512 + tg, av);
        st_cv(awt + b*512 + tg, ld_cv(awt + b*512 + tg) + av);
        attnOut[((size_t)t*32 + b)*512 + tg] = av;
        sawL[tid] = av;
      }
      __syncthreads();
      {
        float accd = 0.f;
        const float* eb = enc + ((size_t)b*512 + t0)*512 + tid;
        for (int tau = 0; tau < 64; ++tau) accd = fmaf(sawL[tau], eb[(size_t)tau*512], accd);
        at_add(xcatA + (size_t)b*1792 + 256 + tid, accd);
        at_add(xcatD + (size_t)b*2560 + tid, accd);
      }
    }
    gridbar(bars + (size_t)(bi++)*288);

    // ---- P5: gatesD (all blocks, atomics into GD) ----
    gates_phase<320, 2560, 160>(smWd, xs, xcatD, GD, jt, kc, tid);
    gridbar(bars + (size_t)(bi++)*288);
  }

  // ---- epilogue: cellD(500), then out_proj(500) ----
  if (blk < 32)
    cell_phase(GD, biasD, dc, xcatD, 2560, 1536, nullptr, 0, 0, blk, tid);
  gridbar(bars + (size_t)(bi++)*288);
  if (blk < 32)
    out_proj_b(blk, tid, lane, wv, 500, xcatD, wm, bm, wg, bg, melOut, gateOut, xdS);
}

// ---------------- launch ----------------
extern "C" void kernel_launch(void* const* d_in, const int* in_sizes, int n_in,
                              void* d_out, int out_size, void* d_ws, size_t ws_size,
                              hipStream_t stream){
  if (ws_size < WS_NEEDED) return;  // diagnostic: absmax==max|ref| => ws too small

  const float* enc    = (const float*)d_in[0];
  const float* mels   = (const float*)d_in[1];
  const unsigned char* mask = (const unsigned char*)d_in[2];
  const float* w_pre1 = (const float*)d_in[3];
  const float* b_pre1 = (const float*)d_in[4];
  const float* w_pre2 = (const float*)d_in[5];
  const float* b_pre2 = (const float*)d_in[6];
  const float* wih_a  = (const float*)d_in[7];
  const float* whh_a  = (const float*)d_in[8];
  const float* bih_a  = (const float*)d_in[9];
  const float* bhh_a  = (const float*)d_in[10];
  const float* wq     = (const float*)d_in[11];
  const float* bq     = (const float*)d_in[12];
  const float* wk     = (const float*)d_in[13];
  const float* bk     = (const float*)d_in[14];
  const float* conv_w = (const float*)d_in[15];
  const float* conv_b = (const float*)d_in[16];
  const float* wl     = (const float*)d_in[17];
  const float* bl     = (const float*)d_in[18];
  const float* wa     = (const float*)d_in[19];
  const float* ba     = (const float*)d_in[20];
  const float* wih_d  = (const float*)d_in[21];
  const float* whh_d  = (const float*)d_in[22];
  const float* bih_d  = (const float*)d_in[23];
  const float* bhh_d  = (const float*)d_in[24];
  const float* wm     = (const float*)d_in[25];
  const float* bm     = (const float*)d_in[26];
  const float* wg     = (const float*)d_in[27];
  const float* bg     = (const float*)d_in[28];

  float* W = (float*)d_ws;
  float* mkT   = W + OFF_MKT;
  float* ac    = W + OFF_AC;
  float* dc    = W + OFF_DC;
  float* aw    = W + OFF_AW;
  float* awt   = W + OFF_AWT;
  unsigned* bars = (unsigned*)(W + OFF_BARS);
  float* GA    = W + OFF_GA;
  float* GD    = W + OFF_GD;
  float* xcatA = W + OFF_XA;
  float* xcatD = W + OFF_XD;
  float* redG  = W + OFF_RED;
  float* biasA = W + OFF_BIASA;
  float* biasD = W + OFF_BIASD;
  float* wfold = W + OFF_WFOLD;
  float* qbias = W + OFF_QBIAS;
  float* wqT   = W + OFF_WQT;
  unsigned short* WaT = (unsigned short*)((char*)d_ws + OFF_WAT_BYTES);
  unsigned short* WdT = (unsigned short*)((char*)d_ws + OFF_WDT_BYTES);
  bf16* pre2b = (bf16*)((char*)d_ws + OFF_PRE2B_BYTES);

  float* out    = (float*)d_out;
  float* melOut = out + OUT_MEL;
  float* gateOut= out + OUT_GATE;
  float* attnOut= out + OUT_ATTN;

  static int smem_set = 0;
  if (!smem_set){
    hipFuncSetAttribute((const void*)k_decoder,
                        hipFuncAttributeMaxDynamicSharedMemorySize, SMEM_TOTAL);
    smem_set = 1;
  }

  // ---- prep ----
  k_zero<<<(int)((ZERO_LEN + 255)/256), 256, 0, stream>>>(W + OFF_AC, (int)ZERO_LEN);
  k_bias<<<16, 256, 0, stream>>>(bih_a, bhh_a, biasA);
  k_bias<<<16, 256, 0, stream>>>(bih_d, bhh_d, biasD);
  k_fold<<<1, 128, 0, stream>>>(conv_w, conv_b, wl, bl, bq, wfold, qbias);
  k_wqT<<<512, 256, 0, stream>>>(wq, wqT);
  k_trans<<<dim3(64, 12), 256, 0, stream>>>(wih_a, 768,  WaT, 0,    224, 28672);
  k_trans<<<dim3(64, 16), 256, 0, stream>>>(whh_a, 1024, WaT, 768,  224, 28672);
  k_trans<<<dim3(64, 24), 256, 0, stream>>>(wih_d, 1536, WdT, 0,    320, 40960);
  k_trans<<<dim3(64, 16), 256, 0, stream>>>(whh_d, 1024, WdT, 1536, 320, 40960);
  k_prenet<<<dim3(32, 63), 256, 0, stream>>>(mels, w_pre1, b_pre1, w_pre2, b_pre2, pre2b);
  k_memkeys<<<dim3(32, 64), 128, 0, stream>>>(enc, wk, bk, mkT);

  // ---- the whole 501-step recurrence: one persistent kernel ----
  k_decoder<<<256, 512, SMEM_TOTAL, stream>>>(WaT, WdT, biasA, biasD, pre2b, mkT, enc, mask,
                                              wqT, qbias, wfold, wa, ba, wm, bm, wg, bg,
                                              xcatA, xcatD, ac, dc, aw, awt,
                                              GA, GD, redG, bars,
                                              melOut, gateOut, attnOut);
}

// Round 7
// 162937.329 us; speedup vs baseline: 1.2323x; 1.0425x over previous
//
#include <hip/hip_runtime.h>
#include <hip/hip_bf16.h>

// B=32, T_ENC=512, steps TD=501, D_ENC=512, N_MEL=160, H=1024, 4H=4096
// aLSTM K = 256(pre)+512(ctx)+1024(ah) = 1792 ; dLSTM K = 512(ctx)+1024(ah)+1024(dh) = 2560
// Persistent kernel v6: v5 structure (LDS weights, bypass mutable state, tree barrier)
// + XCD-residency plan: dur tracked FETCH_SIZE at ~200 GB/s across v2b-v5, so make all
// hot read-only data L2-resident per XCD: b->XCD affinity (xcd=blk&7, b in [4*xcd,4*xcd+4)),
// enc/wq/wm in bf16 (hot set ~3.9 MB/XCD < 4 MB L2), nt stores for outputs,
// per-XCD barrier go-lines.

typedef __hip_bfloat16 bf16;

__device__ __forceinline__ float b2f(bf16 x){ return __bfloat162float(x); }
__device__ __forceinline__ bf16 f2b(float x){ return __float2bfloat16(x); }
__device__ __forceinline__ unsigned short f2bu(float x){
  union { bf16 h; unsigned short u; } cv; cv.h = __float2bfloat16(x); return cv.u;
}
__device__ __forceinline__ float us2f(unsigned short u){
  return __uint_as_float(((unsigned)u) << 16);
}
__device__ __forceinline__ float sig_s(float x){
  if (x > 30.f) return 1.f; if (x < -30.f) return 0.f;
  return 1.f/(1.f+__expf(-x)); }
__device__ __forceinline__ float tanh_s(float x){
  if (x > 15.f) return 1.f; if (x < -15.f) return -1.f;
  float e=__expf(2.f*x); return 1.f-2.f/(e+1.f); }

// coherent bypass load/store (agent scope, relaxed -> no cache fills/maintenance)
__device__ __forceinline__ float ld_cv(const float* p){
  return __hip_atomic_load(p, __ATOMIC_RELAXED, __HIP_MEMORY_SCOPE_AGENT);
}
__device__ __forceinline__ void st_cv(float* p, float v){
  __hip_atomic_store(p, v, __ATOMIC_RELAXED, __HIP_MEMORY_SCOPE_AGENT);
}
__device__ __forceinline__ float2 ld_cv2(const float* p){
  union { double d; float2 f; } u;
  u.d = __hip_atomic_load((const double*)p, __ATOMIC_RELAXED, __HIP_MEMORY_SCOPE_AGENT);
  return u.f;
}
__device__ __forceinline__ void st_cv2(float* p, float2 v){
  union { double d; float2 f; } u; u.f = v;
  __hip_atomic_store((double*)p, u.d, __ATOMIC_RELAXED, __HIP_MEMORY_SCOPE_AGENT);
}
__device__ __forceinline__ void at_add(float* p, float v){
  __hip_atomic_fetch_add(p, v, __ATOMIC_RELAXED, __HIP_MEMORY_SCOPE_AGENT);
}

// ---------------- workspace layout (fp32 elements unless noted) ----------------
constexpr size_t OFF_MKT = 0;                         // mkT fp32 [32][128][512]
constexpr size_t OFF_AC  = OFF_MKT + 32ull*128*512;
constexpr size_t OFF_DC  = OFF_AC + 32*1024;
constexpr size_t OFF_AW  = OFF_DC + 32*1024;
constexpr size_t OFF_AWT = OFF_AW + 32*512;
constexpr size_t OFF_BARS= OFF_AWT + 32*512;          // 2560 instances x 512 uints
constexpr size_t S_BARS  = 2560ull*512;
constexpr size_t OFF_GA  = OFF_BARS + S_BARS;         // 32 x 4096 accum
constexpr size_t OFF_GD  = OFF_GA + 32*4096;
constexpr size_t OFF_XA  = OFF_GD + 32*4096;          // xcatA [32][1792] = [pre|ctx|ah]
constexpr size_t ZERO_LEN = OFF_XA - OFF_AC;
constexpr size_t OFF_XD  = OFF_XA + 32*1792;          // xcatD [32][2560] = [ctx|ah|dh]
constexpr size_t OFF_RED = OFF_XD + 32*2560;          // redG [32][8][2]
constexpr size_t OFF_BIASA = OFF_RED + 512;
constexpr size_t OFF_BIASD = OFF_BIASA + 4096;
constexpr size_t OFF_WFOLD = OFF_BIASD + 4096;        // 128 x 62
constexpr size_t OFF_QBIAS = OFF_WFOLD + 7936;        // 128 = bq + bl + wl@conv_b
constexpr size_t OFF_F32_END = OFF_QBIAS + 128;

constexpr size_t OFF_PRE2B_BYTES = ((OFF_F32_END*4 + 255)/256)*256;
constexpr size_t S_PRE2B = 501ull*32*256;                        // bf16
constexpr size_t OFF_WAT_BYTES = ((OFF_PRE2B_BYTES + S_PRE2B*2 + 255)/256)*256;
constexpr size_t S_WAT = 1792ull*4096;                           // bf16, per-block slices
constexpr size_t OFF_WDT_BYTES = OFF_WAT_BYTES + S_WAT*2;
constexpr size_t S_WDT = 2560ull*4096;
constexpr size_t OFF_ENCB_BYTES = OFF_WDT_BYTES + S_WDT*2;       // enc bf16 [32][512][512]
constexpr size_t S_ENCB = 32ull*512*512;
constexpr size_t OFF_WQTB_BYTES = OFF_ENCB_BYTES + S_ENCB*2;     // wqT bf16 [1024][128]
constexpr size_t S_WQTB = 1024ull*128;
constexpr size_t OFF_WMB_BYTES = OFF_WQTB_BYTES + S_WQTB*2;      // wm+wg bf16 [161][1536]
constexpr size_t S_WMB = 161ull*1536;
constexpr size_t WS_NEEDED = OFF_WMB_BYTES + S_WMB*2;            // ~77.1 MB

// LDS: Wa slice 57344 B | Wd slice 81920 B | scratch 23552 B
constexpr int LDS_WA = 57344;
constexpr int LDS_WD = 81920;
constexpr int LDS_SCR = 23552;
constexpr int SMEM_TOTAL = LDS_WA + LDS_WD + LDS_SCR;   // 162,816 <= 163,840

// output offsets (fp32 elements in d_out)
constexpr size_t OUT_MEL  = 0;
constexpr size_t OUT_GATE = 501ull*32*160;
constexpr size_t OUT_ATTN = OUT_GATE + 501ull*32;

// ---------------- prep kernels ----------------
__global__ void k_zero(float* __restrict__ p, int n){
  int i = blockIdx.x*256 + threadIdx.x;
  if (i < n) p[i] = 0.f;
}

__global__ void k_bias(const float* __restrict__ b1, const float* __restrict__ b2,
                       float* __restrict__ out){
  int i = blockIdx.x*256 + threadIdx.x;
  if (i < 4096) out[i] = b1[i] + b2[i];
}

// fold wl (128x32) into conv weights (32x62) -> wfold[128][62]; qbias = bq+bl+wl@cb
__global__ void k_fold(const float* __restrict__ cw, const float* __restrict__ cb,
                       const float* __restrict__ wl, const float* __restrict__ bl,
                       const float* __restrict__ bq,
                       float* __restrict__ wfold, float* __restrict__ qbias){
  int c = threadIdx.x;  // 128 threads, 1 block
  for (int kk = 0; kk < 62; ++kk){
    float a = 0.f;
    for (int o = 0; o < 32; ++o) a += wl[c*32 + o]*cw[o*62 + kk];
    wfold[c*62 + kk] = a;
  }
  float q = bq[c] + bl[c];
  for (int o = 0; o < 32; ++o) q += wl[c*32 + o]*cb[o];
  qbias[c] = q;
}

// wqTb[k][c] = bf16(wq[c][k])
__global__ __launch_bounds__(256) void k_wqTb(const float* __restrict__ wq,
                                              unsigned short* __restrict__ wqTb){
  int idx = blockIdx.x*256 + threadIdx.x;   // 131072
  int k = idx >> 7, c = idx & 127;
  wqTb[idx] = f2bu(wq[(size_t)c*1024 + k]);
}

// wmb rows 0..159 = wm, row 160 = wg (bf16)
__global__ __launch_bounds__(256) void k_wmb(const float* __restrict__ wm,
                                             const float* __restrict__ wg,
                                             unsigned short* __restrict__ wmb){
  int idx = blockIdx.x*256 + threadIdx.x;   // 161*1536 = 247296
  if (idx >= 161*1536) return;
  int r = idx / 1536, k = idx - r*1536;
  wmb[idx] = f2bu(r < 160 ? wm[(size_t)r*1536 + k] : wg[k]);
}

// encB = bf16(enc), grid-stride
__global__ __launch_bounds__(256) void k_encb(const float* __restrict__ enc,
                                              unsigned short* __restrict__ encB){
  for (size_t i = (size_t)blockIdx.x*256 + threadIdx.x; i < S_ENCB;
       i += (size_t)gridDim.x*256)
    encB[i] = f2bu(enc[i]);
}

// W^T bf16, laid out as per-block contiguous slices:
// slice = (kc*32 + jt); within: (klocal>>2)*512 + jl*4 + (klocal&3)  (ushorts)
__global__ __launch_bounds__(256) void k_trans(const float* __restrict__ src, int C,
    unsigned short* __restrict__ dst, int koff, int CH, int SLICE){
  __shared__ unsigned short tile[64][65];
  int r0 = blockIdx.x*64, c0 = blockIdx.y*64;
  int tx = threadIdx.x & 63, ty = threadIdx.x >> 6;
  for (int rr = ty; rr < 64; rr += 4)
    tile[rr][tx] = f2bu(src[(size_t)(r0+rr)*C + c0 + tx]);
  __syncthreads();
  for (int rr = ty; rr < 64; rr += 4){
    int k = koff + c0 + rr;
    int kcc = k / CH, kl = k - kcc*CH;
    int j = r0 + tx, jtt = j >> 7, jl = j & 127;
    dst[(size_t)(kcc*32 + jtt)*SLICE + (size_t)(kl >> 2)*512 + jl*4 + (kl & 3)] = tile[tx][rr];
  }
}

// prenet -> pre2b[tt][b][j] (bf16)
__global__ __launch_bounds__(256) void k_prenet(const float* __restrict__ mels,
    const float* __restrict__ w1, const float* __restrict__ b1,
    const float* __restrict__ w2, const float* __restrict__ b2,
    bf16* __restrict__ pre2){
  __shared__ float mel[160];
  __shared__ float x1[256];
  int b = blockIdx.x, tid = threadIdx.x;
  for (int ti = 0; ti < 8; ++ti){
    int tt = blockIdx.y*8 + ti;
    if (tt >= 501) break;
    if (tid < 160) mel[tid] = (tt == 0) ? 0.f : mels[((size_t)b*500 + (tt-1))*160 + tid];
    __syncthreads();
    float a = b1[tid];
    for (int k = 0; k < 160; ++k) a += mel[k]*w1[tid*160 + k];
    x1[tid] = fmaxf(a, 0.f);
    __syncthreads();
    float a2 = b2[tid];
    for (int k = 0; k < 256; ++k) a2 += x1[k]*w2[tid*256 + k];
    pre2[((size_t)tt*32 + b)*256 + tid] = f2b(fmaxf(a2, 0.f));
    __syncthreads();
  }
}

// mkT[b][c][t] = dot(enc[b][t][:], wk[c][:]) + bk[c]   (fp32 for softmax precision)
__global__ __launch_bounds__(128) void k_memkeys(const float* __restrict__ enc,
    const float* __restrict__ wk, const float* __restrict__ bk, float* __restrict__ mkT){
  __shared__ float er[512];
  int b = blockIdx.x, tid = threadIdx.x;
  for (int i = 0; i < 8; ++i){
    int t = blockIdx.y*8 + i;
    const float* e = enc + ((size_t)b*512 + t)*512;
    for (int k = tid; k < 512; k += 128) er[k] = e[k];
    __syncthreads();
    float a = bk[tid];
    for (int k = 0; k < 512; ++k) a += er[k]*wk[tid*512 + k];
    mkT[((size_t)b*128 + tid)*512 + t] = a;
    __syncthreads();
  }
}

// ---------------- persistent decoder ----------------
// Tree barrier, one instance per use (no reset/ABA). Per instance (512 uints):
// grp[g] at g*16 (16 groups), root at 256, go[xcd] at 288+xcd*16 (8 lines).
// Releaser broadcasts to 8 per-XCD go lines; each block polls only its XCD's line.
__device__ __forceinline__ void gridbar(unsigned* base, int xcd){
  asm volatile("s_waitcnt vmcnt(0) lgkmcnt(0)" ::: "memory");
  __syncthreads();
  if (threadIdx.x == 0){
    unsigned* grp  = base + ((blockIdx.x >> 4) << 4);
    unsigned* root = base + 256;
    if (__hip_atomic_fetch_add(grp, 1u, __ATOMIC_RELAXED, __HIP_MEMORY_SCOPE_AGENT) == 15u){
      if (__hip_atomic_fetch_add(root, 1u, __ATOMIC_RELAXED, __HIP_MEMORY_SCOPE_AGENT) == 15u){
        #pragma unroll
        for (int x = 0; x < 8; ++x)
          __hip_atomic_store(base + 288 + x*16, 1u,
                             __ATOMIC_RELAXED, __HIP_MEMORY_SCOPE_AGENT);
      }
    }
    unsigned* go = base + 288 + xcd*16;
    while (!__hip_atomic_load(go, __ATOMIC_RELAXED, __HIP_MEMORY_SCOPE_AGENT))
      __builtin_amdgcn_s_sleep(8);
  }
  __syncthreads();
}

// skinny-GEMM k-chunk from LDS-resident weights; accumulate into G via f32 atomics.
// block = (jt = blk&31, kc = blk>>5); threads 512 = 128 j x 4 b-groups(8 b).
template<int CH, int KS, int HK>
__device__ __forceinline__ void gates_phase(const unsigned short* __restrict__ smW,
    float* xs, const float* xcat, float* G, int jt, int kc, int tid){
  const int jl = tid & 127, bg = tid >> 7;
  float acc[8];
  #pragma unroll
  for (int i = 0; i < 8; ++i) acc[i] = 0.f;
  const int k0 = kc*CH;
  for (int h = 0; h < CH/HK; ++h){
    __syncthreads();
    for (int i = tid; i < 16*HK; i += 512){
      int b = i/(HK/2), kp = i - b*(HK/2);
      ((float2*)xs)[i] = ld_cv2(xcat + (size_t)b*KS + k0 + h*HK + 2*kp);
    }
    __syncthreads();
    for (int kk = 0; kk < HK; kk += 4){
      const ushort4 w4 = *(const ushort4*)(smW + (size_t)((h*HK + kk) >> 2)*512 + jl*4);
      const float w0 = us2f(w4.x), w1 = us2f(w4.y), w2 = us2f(w4.z), w3 = us2f(w4.w);
      #pragma unroll
      for (int bb = 0; bb < 8; ++bb){
        const float4 xv = *(const float4*)&xs[(bg*8 + bb)*HK + kk];
        acc[bb] = fmaf(xv.x, w0, acc[bb]);
        acc[bb] = fmaf(xv.y, w1, acc[bb]);
        acc[bb] = fmaf(xv.z, w2, acc[bb]);
        acc[bb] = fmaf(xv.w, w3, acc[bb]);
      }
    }
  }
  #pragma unroll
  for (int bb = 0; bb < 8; ++bb)
    at_add(G + (size_t)(bg*8 + bb)*4096 + jt*128 + jl, acc[bb]);
}

// LSTM cell: read accumulated G, re-zero it, nonlinearity, write h (bypass).
// 32 logical blocks (ord 0..31) x 512 threads, thread owns a u-pair.
__device__ __forceinline__ void cell_phase(float* G,
    const float* __restrict__ bias, float* cst,
    float* h0, int h0stride, int h0off,
    float* h1, int h1stride, int h1off,
    int ord, int tid){
  int idx = (ord*512 + tid)*2;
  int b = idx >> 10, u = idx & 1023;
  float* gb = G + (size_t)b*4096 + u;
  float2 gi = ld_cv2(gb), gf = ld_cv2(gb+1024), gg = ld_cv2(gb+2048), go = ld_cv2(gb+3072);
  float2 z = make_float2(0.f, 0.f);
  st_cv2(gb, z); st_cv2(gb+1024, z); st_cv2(gb+2048, z); st_cv2(gb+3072, z);
  gi.x += bias[u];      gi.y += bias[u+1];
  gf.x += bias[1024+u]; gf.y += bias[1024+u+1];
  gg.x += bias[2048+u]; gg.y += bias[2048+u+1];
  go.x += bias[3072+u]; go.y += bias[3072+u+1];
  float2 cp = ld_cv2(cst + idx);
  float cn0 = sig_s(gf.x)*cp.x + sig_s(gi.x)*tanh_s(gg.x);
  float cn1 = sig_s(gf.y)*cp.y + sig_s(gi.y)*tanh_s(gg.y);
  float2 hh = make_float2(sig_s(go.x)*tanh_s(cn0), sig_s(go.y)*tanh_s(cn1));
  st_cv2(cst + idx, make_float2(cn0, cn1));
  st_cv2(h0 + (size_t)b*h0stride + h0off + u, hh);
  if (h1) st_cv2(h1 + (size_t)b*h1stride + h1off + u, hh);
}

// output projection for one b: stage xcatD row into LDS once, 161 bf16 dots, nt stores.
__device__ __forceinline__ void out_proj_b(int b, int tid, int lane, int wv, int t,
    const float* xcatD, const unsigned short* __restrict__ wmb,
    const float* __restrict__ bm, const float* __restrict__ bg,
    float* melOut, float* gateOut, float* xdS){
  for (int i = tid; i < 1280; i += 512)
    ((float2*)xdS)[i] = ld_cv2(xcatD + (size_t)b*2560 + 2*i);
  __syncthreads();
  for (int jo = wv; jo < 161; jo += 8){
    const unsigned short* wrow = wmb + (size_t)jo*1536;
    float a = 0.f;
    for (int k = lane; k < 1536; k += 64){
      float x = (k < 1024) ? xdS[1536 + k] : xdS[k - 1024];   // h = [dh | ctx]
      a = fmaf(x, us2f(wrow[k]), a);
    }
    #pragma unroll
    for (int off = 32; off; off >>= 1) a += __shfl_down(a, off, 64);
    if (lane == 0){
      if (jo < 160) st_cv(melOut + ((size_t)t*32 + b)*160 + jo, a + bm[jo]);
      else st_cv(gateOut + t*32 + b, a + bg[0]);
    }
  }
}

__global__ __launch_bounds__(512) void k_decoder(
    const unsigned short* __restrict__ WaT, const unsigned short* __restrict__ WdT,
    const float* __restrict__ biasA, const float* __restrict__ biasD,
    const bf16* __restrict__ pre2b, const float* __restrict__ mkT,
    const unsigned short* __restrict__ encB, const unsigned char* __restrict__ mask,
    const unsigned short* __restrict__ wqTb, const float* __restrict__ qbias,
    const float* __restrict__ wfold, const float* __restrict__ wa,
    const float* __restrict__ ba, const unsigned short* __restrict__ wmb,
    const float* __restrict__ bm, const float* __restrict__ bg,
    float* xcatA, float* xcatD, float* ac, float* dc,
    float* aw, float* awt, float* GA, float* GD,
    float* redG, unsigned* bars,
    float* melOut, float* gateOut, float* attnOut)
{
  extern __shared__ __align__(16) char sm[];
  unsigned short* smWa = (unsigned short*)sm;
  unsigned short* smWd = (unsigned short*)(sm + LDS_WA);
  char* scr = sm + LDS_WA + LDS_WD;
  float* xs   = (float*)scr;               // gates staging [0,20480)
  float* xdS  = (float*)scr;               // out_proj [0,10240)
  float* ahS  = (float*)scr;               // P3 [0,4096)
  float* qpP  = (float*)(scr + 4096);      // P3 [4096,6144)
  float* sqS  = (float*)(scr + 6144);      // [6144,6656)
  float* eT   = (float*)(scr + 6656);      // [6656,6912)  persists P3->P4
  float* sawL = (float*)(scr + 6912);      // [6912,7168)  P4 internal
  float* s0   = (float*)(scr + 7168);      // [7168,7552)
  float* s1   = (float*)(scr + 7552);      // [7552,7936)

  const int blk = blockIdx.x, tid = threadIdx.x;
  const int lane = tid & 63, wv = tid >> 6;
  const int jt = blk & 31, kc = blk >> 5;
  // XCD-affinity mapping (dispatch round-robins XCDs: xcd = blk & 7)
  const int xcd  = blk & 7;
  const int loc8 = blk >> 3;                 // 0..31 within XCD
  const int batt = xcd*4 + (loc8 & 3);       // attention batch for this block
  const int ttat = loc8 >> 2;                // attention t-tile (0..7)
  const int role = loc8 >> 2;                // role group for cell/out/prestage
  const int ord  = xcd*4 + (loc8 & 3);       // 0..31 ordinal within a role

  // ---- one-time: weight slices -> LDS; init xcat (bypass stores) ----
  {
    const ushort4* sa = (const ushort4*)(WaT + (size_t)(kc*32 + jt)*28672);
    ushort4* da = (ushort4*)smWa;
    for (int i = tid; i < 7168; i += 512) da[i] = sa[i];
    const ushort4* sd = (const ushort4*)(WdT + (size_t)(kc*32 + jt)*40960);
    ushort4* dd = (ushort4*)smWd;
    for (int i = tid; i < 10240; i += 512) dd[i] = sd[i];
  }
  for (int idx = blk*512 + tid; idx < 32*1792; idx += 131072){
    int b = idx / 1792, i = idx - b*1792;
    st_cv(xcatA + idx, (i < 256) ? b2f(pre2b[b*256 + i]) : 0.f);
  }
  for (int idx = blk*512 + tid; idx < 32*2560; idx += 131072) st_cv(xcatD + idx, 0.f);

  int bi = 0;
  gridbar(bars + (size_t)(bi++)*512, xcd);

  for (int t = 0; t < 501; ++t){
    // ---- P1: gatesA (all blocks -> GA) | cellD(t-1) (role 0) ----
    gates_phase<224, 1792, 112>(smWa, xs, xcatA, GA, jt, kc, tid);
    if (role == 0 && t > 0)
      cell_phase(GD, biasD, dc, xcatD, 2560, 1536, nullptr, 0, 0, ord, tid);
    gridbar(bars + (size_t)(bi++)*512, xcd);

    // ---- P2: cellA (role 0) | out(t-1) (role 1) | pre-stage(t+1) (role 2) ----
    if (role == 0){
      cell_phase(GA, biasA, ac, xcatA, 1792, 768, xcatD, 2560, 512, ord, tid);
    } else if (role == 1){
      if (t > 0)
        out_proj_b(ord, tid, lane, wv, t-1, xcatD, wmb, bm, bg, melOut, gateOut, xdS);
    } else if (role == 2){
      if (t < 500){
        const bf16* ps = pre2b + ((size_t)(t+1)*32 + ord)*256;
        for (int i = tid; i < 128; i += 512)
          st_cv2(xcatA + (size_t)ord*1792 + 2*i,
                 make_float2(b2f(ps[2*i]), b2f(ps[2*i+1])));
      }
    }
    gridbar(bars + (size_t)(bi++)*512, xcd);

    // ---- P3: attention energies + fused conv (block -> (batt, ttat)) ----
    {
      int b = batt, t0 = ttat*64;
      if (tid < 32){  // zero this block's ctx chunk (accumulated by P4 atomics)
        float2 z = make_float2(0.f, 0.f);
        st_cv2(xcatA + (size_t)b*1792 + 256 + t0 + 2*tid, z);
        st_cv2(xcatD + (size_t)b*2560 + t0 + 2*tid, z);
      }
      // stage conv windows: pos in [t0-15, t0+79), 94 each for aw and awt
      for (int i = tid; i < 188; i += 512){
        int ch = (i >= 94), p2 = ch ? i-94 : i;
        int pos = t0 + p2 - 15;
        float v = (pos >= 0 && pos < 512)
                ? (ch ? ld_cv(awt + b*512 + pos) : ld_cv(aw + b*512 + pos)) : 0.f;
        (ch ? s1 : s0)[p2] = v;
      }
      ((float2*)ahS)[tid] = ld_cv2(xcatA + (size_t)b*1792 + 768 + 2*tid);
      __syncthreads();
      {  // query partials (redundant across the 8 tt-blocks of b; wqTb L2-hot)
        int c = tid & 127, kq = tid >> 7;
        const float* ap = ahS + kq*256;
        const unsigned short* wp = wqTb + (size_t)(kq*256)*128 + c;
        float p = 0.f;
        for (int k = 0; k < 256; ++k) p = fmaf(ap[k], us2f(wp[(size_t)k*128]), p);
        qpP[kq*128 + c] = p;
      }
      __syncthreads();
      if (tid < 128)
        sqS[tid] = qpP[tid] + qpP[128+tid] + qpP[256+tid] + qpP[384+tid] + qbias[tid];
      __syncthreads();
      int tl = tid & 63, cg = tid >> 6;
      const float* mkb = mkT + (size_t)b*65536 + t0 + tl;
      float a = 0.f;
      for (int ci = 0; ci < 16; ++ci){
        int c = cg*16 + ci;
        const float* wf = wfold + c*62;   // lane-uniform -> scalar loads
        float lc = 0.f;
        #pragma unroll
        for (int k = 0; k < 31; ++k)
          lc = fmaf(wf[k], s0[tl+k], fmaf(wf[31+k], s1[tl+k], lc));
        float s = sqS[c] + mkb[(size_t)c*512] + lc;
        a = fmaf(tanh_s(s), wa[c], a);
      }
      qpP[cg*64 + tl] = a;
      __syncthreads();
      if (tid < 64){
        float e = ba[0];
        #pragma unroll
        for (int g = 0; g < 8; ++g) e += qpP[g*64 + tid];
        if (mask[b*512 + t0 + tid]) e = -1e30f;
        eT[tid] = e;
        float m = e;
        #pragma unroll
        for (int off = 32; off; off >>= 1) m = fmaxf(m, __shfl_xor(m, off, 64));
        float pe = __expf(e - m), ss = pe;
        #pragma unroll
        for (int off = 32; off; off >>= 1) ss += __shfl_xor(ss, off, 64);
        if (tid == 0)
          st_cv2(redG + (size_t)(b*8 + ttat)*2, make_float2(m, ss));
      }
    }
    gridbar(bars + (size_t)(bi++)*512, xcd);

    // ---- P4: softmax finish + ctx partial (atomic reduce); encB L2-resident ----
    {
      int b = batt, t0 = ttat*64;
      if (tid < 64){
        float M = -1e30f, S = 0.f;
        float2 ms[8];
        #pragma unroll
        for (int i = 0; i < 8; ++i){
          ms[i] = ld_cv2(redG + (size_t)(b*8 + i)*2);
          M = fmaxf(M, ms[i].x);
        }
        #pragma unroll
        for (int i = 0; i < 8; ++i) S += ms[i].y*__expf(ms[i].x - M);
        float av = __expf(eT[tid] - M)/S;
        int tg = t0 + tid;
        st_cv(aw + b*512 + tg, av);
        st_cv(awt + b*512 + tg, ld_cv(awt + b*512 + tg) + av);
        st_cv(attnOut + ((size_t)t*32 + b)*512 + tg, av);
        sawL[tid] = av;
      }
      __syncthreads();
      {
        float accd = 0.f;
        const unsigned short* eb = encB + ((size_t)b*512 + t0)*512 + tid;
        for (int tau = 0; tau < 64; ++tau)
          accd = fmaf(sawL[tau], us2f(eb[(size_t)tau*512]), accd);
        at_add(xcatA + (size_t)b*1792 + 256 + tid, accd);
        at_add(xcatD + (size_t)b*2560 + tid, accd);
      }
    }
    gridbar(bars + (size_t)(bi++)*512, xcd);

    // ---- P5: gatesD (all blocks -> GD) ----
    gates_phase<320, 2560, 160>(smWd, xs, xcatD, GD, jt, kc, tid);
    gridbar(bars + (size_t)(bi++)*512, xcd);
  }

  // ---- epilogue: cellD(500), then out_proj(500) ----
  if (role == 0)
    cell_phase(GD, biasD, dc, xcatD, 2560, 1536, nullptr, 0, 0, ord, tid);
  gridbar(bars + (size_t)(bi++)*512, xcd);
  if (role == 1)
    out_proj_b(ord, tid, lane, wv, 500, xcatD, wmb, bm, bg, melOut, gateOut, xdS);
}

// ---------------- launch ----------------
extern "C" void kernel_launch(void* const* d_in, const int* in_sizes, int n_in,
                              void* d_out, int out_size, void* d_ws, size_t ws_size,
                              hipStream_t stream){
  if (ws_size < WS_NEEDED) return;  // diagnostic: absmax==max|ref| => ws too small

  const float* enc    = (const float*)d_in[0];
  const float* mels   = (const float*)d_in[1];
  const unsigned char* mask = (const unsigned char*)d_in[2];
  const float* w_pre1 = (const float*)d_in[3];
  const float* b_pre1 = (const float*)d_in[4];
  const float* w_pre2 = (const float*)d_in[5];
  const float* b_pre2 = (const float*)d_in[6];
  const float* wih_a  = (const float*)d_in[7];
  const float* whh_a  = (const float*)d_in[8];
  const float* bih_a  = (const float*)d_in[9];
  const float* bhh_a  = (const float*)d_in[10];
  const float* wq     = (const float*)d_in[11];
  const float* bq     = (const float*)d_in[12];
  const float* wk     = (const float*)d_in[13];
  const float* bk     = (const float*)d_in[14];
  const float* conv_w = (const float*)d_in[15];
  const float* conv_b = (const float*)d_in[16];
  const float* wl     = (const float*)d_in[17];
  const float* bl     = (const float*)d_in[18];
  const float* wa     = (const float*)d_in[19];
  const float* ba     = (const float*)d_in[20];
  const float* wih_d  = (const float*)d_in[21];
  const float* whh_d  = (const float*)d_in[22];
  const float* bih_d  = (const float*)d_in[23];
  const float* bhh_d  = (const float*)d_in[24];
  const float* wm     = (const float*)d_in[25];
  const float* bm     = (const float*)d_in[26];
  const float* wg     = (const float*)d_in[27];
  const float* bg     = (const float*)d_in[28];

  float* W = (float*)d_ws;
  float* mkT   = W + OFF_MKT;
  float* ac    = W + OFF_AC;
  float* dc    = W + OFF_DC;
  float* aw    = W + OFF_AW;
  float* awt   = W + OFF_AWT;
  unsigned* bars = (unsigned*)(W + OFF_BARS);
  float* GA    = W + OFF_GA;
  float* GD    = W + OFF_GD;
  float* xcatA = W + OFF_XA;
  float* xcatD = W + OFF_XD;
  float* redG  = W + OFF_RED;
  float* biasA = W + OFF_BIASA;
  float* biasD = W + OFF_BIASD;
  float* wfold = W + OFF_WFOLD;
  float* qbias = W + OFF_QBIAS;
  unsigned short* WaT  = (unsigned short*)((char*)d_ws + OFF_WAT_BYTES);
  unsigned short* WdT  = (unsigned short*)((char*)d_ws + OFF_WDT_BYTES);
  unsigned short* encB = (unsigned short*)((char*)d_ws + OFF_ENCB_BYTES);
  unsigned short* wqTb = (unsigned short*)((char*)d_ws + OFF_WQTB_BYTES);
  unsigned short* wmb  = (unsigned short*)((char*)d_ws + OFF_WMB_BYTES);
  bf16* pre2b = (bf16*)((char*)d_ws + OFF_PRE2B_BYTES);

  float* out    = (float*)d_out;
  float* melOut = out + OUT_MEL;
  float* gateOut= out + OUT_GATE;
  float* attnOut= out + OUT_ATTN;

  static int smem_set = 0;
  if (!smem_set){
    hipFuncSetAttribute((const void*)k_decoder,
                        hipFuncAttributeMaxDynamicSharedMemorySize, SMEM_TOTAL);
    smem_set = 1;
  }

  // ---- prep ----
  k_zero<<<(int)((ZERO_LEN + 255)/256), 256, 0, stream>>>(W + OFF_AC, (int)ZERO_LEN);
  k_bias<<<16, 256, 0, stream>>>(bih_a, bhh_a, biasA);
  k_bias<<<16, 256, 0, stream>>>(bih_d, bhh_d, biasD);
  k_fold<<<1, 128, 0, stream>>>(conv_w, conv_b, wl, bl, bq, wfold, qbias);
  k_wqTb<<<512, 256, 0, stream>>>(wq, wqTb);
  k_wmb<<<966, 256, 0, stream>>>(wm, wg, wmb);
  k_encb<<<2048, 256, 0, stream>>>(enc, encB);
  k_trans<<<dim3(64, 12), 256, 0, stream>>>(wih_a, 768,  WaT, 0,    224, 28672);
  k_trans<<<dim3(64, 16), 256, 0, stream>>>(whh_a, 1024, WaT, 768,  224, 28672);
  k_trans<<<dim3(64, 24), 256, 0, stream>>>(wih_d, 1536, WdT, 0,    320, 40960);
  k_trans<<<dim3(64, 16), 256, 0, stream>>>(whh_d, 1024, WdT, 1536, 320, 40960);
  k_prenet<<<dim3(32, 63), 256, 0, stream>>>(mels, w_pre1, b_pre1, w_pre2, b_pre2, pre2b);
  k_memkeys<<<dim3(32, 64), 128, 0, stream>>>(enc, wk, bk, mkT);

  // ---- the whole 501-step recurrence: one persistent kernel ----
  k_decoder<<<256, 512, SMEM_TOTAL, stream>>>(WaT, WdT, biasA, biasD, pre2b, mkT,
                                              encB, mask, wqTb, qbias, wfold, wa, ba,
                                              wmb, bm, bg,
                                              xcatA, xcatD, ac, dc, aw, awt,
                                              GA, GD, redG, bars,
                                              melOut, gateOut, attnOut);
}